// Round 1
// baseline (35853.043 us; speedup 1.0000x reference)
//
#include <hip/hip_runtime.h>
#include <hip/hip_bf16.h>

#define B_  64
#define T_  1024
#define D_  512
#define H_  1024
#define G4H (4 * H_)
#define NWG 256
#define KX  16   // 512/32 K-steps for x part
#define KH  32   // 1024/32 K-steps for h part

typedef __attribute__((ext_vector_type(8))) short bf16x8;
typedef __attribute__((ext_vector_type(4))) float f32x4;

__device__ __forceinline__ short f2bf(float f) {
    union { float f; unsigned int u; } v;
    v.f = f;
    unsigned int r = v.u + 0x7FFFu + ((v.u >> 16) & 1u);  // RNE
    return (short)(r >> 16);
}

__device__ __forceinline__ float sigmoid_f(float x) {
    return 1.0f / (1.0f + __expf(-x));   // exp overflow -> inf -> 0, safe
}

__device__ __forceinline__ float tanh_f(float x) {
    float ax = fabsf(x);
    float e  = __expf(-2.0f * ax);       // in (0,1], no overflow
    float t  = (1.0f - e) / (1.0f + e);
    return copysignf(t, x);
}

// Persistent cooperative LSTM scan.
// 256 WGs x 256 threads; WG wg owns hidden units j0=4*wg..j0+3 (16 gate cols).
// Wh/Wx slices live in registers as pre-packed bf16 MFMA B-fragments.
// Per-step device-scope flag barrier; h ping-pongs through global (bf16).
__global__ void __launch_bounds__(256, 1)
lstm_persistent(const float* __restrict__ x,     // [B,T,D]
                const float* __restrict__ Wx,    // [D,4H]
                const float* __restrict__ Wh,    // [H,4H]
                const float* __restrict__ bias,  // [4H] (i,f,g,o)
                float* __restrict__ y,           // [B,T,H]
                short* __restrict__ h_buf,       // ws: [2][B][H] bf16
                short* __restrict__ xb_buf,      // ws: [2][B][D] bf16
                int* flags)                      // ws: [NWG]
{
    const int wg   = blockIdx.x;
    const int tid  = threadIdx.x;
    const int lane = tid & 63;
    const int wv   = tid >> 6;        // wave 0..3 -> batches wv*16..wv*16+15
    const int j0   = wg * 4;

    // ---- B-fragment lane mapping (mfma_f32_16x16x32_bf16):
    // lane&15 = B column (tile col c), lane>>4 = k-block, 8 contiguous k elems.
    const int c    = lane & 15;
    const int gate = c >> 2;          // 0..3 = i,f,g,o
    const int hh   = c & 3;           // hidden unit within WG
    const int gcol = gate * H_ + j0 + hh;
    const int kblk = lane >> 4;

    // ---- prologue: pack Wx/Wh slices into register-resident bf16 fragments
    bf16x8 wxf[KX];
#pragma unroll
    for (int ks = 0; ks < KX; ++ks) {
        bf16x8 tf;
#pragma unroll
        for (int e = 0; e < 8; ++e) {
            int k = ks * 32 + kblk * 8 + e;
            tf[e] = f2bf(Wx[k * G4H + gcol]);
        }
        wxf[ks] = tf;
    }
    bf16x8 whf[KH];
#pragma unroll
    for (int ks = 0; ks < KH; ++ks) {
        bf16x8 tf;
#pragma unroll
        for (int e = 0; e < 8; ++e) {
            int k = ks * 32 + kblk * 8 + e;
            tf[e] = f2bf(Wh[k * G4H + gcol]);
        }
        whf[ks] = tf;
    }

    // ---- epilogue lane mapping: lane -> (batch eb, hidden ej) pair
    const int eb = lane & 15;
    const int ej = lane >> 4;
    const float bi = bias[0 * H_ + j0 + ej];
    const float bf = bias[1 * H_ + j0 + ej];
    const float bg = bias[2 * H_ + j0 + ej];
    const float bo = bias[3 * H_ + j0 + ej];

    float cstate = 0.0f;                      // c for (batch bw+eb, hidden j0+ej)

    __shared__ float gbuf[4][16][16];         // per-wave gates tile

    const int bw   = wv * 16;
    const int arow = bw + (lane & 15);        // A-fragment row = batch

    // ---- prologue: convert x_0 -> xb_buf[0] (each WG converts 128 elems)
    if (tid < 128) {
        int m = wg * 128 + tid;               // m in [0, B*D)
        int b = m >> 9, d = m & 511;
        xb_buf[m] = f2bf(x[(b * T_ + 0) * D_ + d]);
    }
    // entry barrier: phase 1 (h_buf[0] zeroed by host-side memset)
    __syncthreads();
    if (tid == 0) {
        __threadfence();
        __hip_atomic_store(&flags[wg], 1, __ATOMIC_RELAXED, __HIP_MEMORY_SCOPE_AGENT);
    }
    while (__hip_atomic_load(&flags[tid], __ATOMIC_RELAXED, __HIP_MEMORY_SCOPE_AGENT) < 1) {}
    __syncthreads();
    __threadfence();

#pragma unroll 1
    for (int t = 0; t < T_; ++t) {
        const int cur = t & 1;
        const int nxt = cur ^ 1;
        const short* hb = h_buf  + cur * (B_ * H_);
        const short* xb = xb_buf + cur * (B_ * D_);

        // 4 independent accumulator chains to break MFMA dep latency
        f32x4 ax0 = {0.f,0.f,0.f,0.f}, ax1 = {0.f,0.f,0.f,0.f};
        f32x4 ah0 = {0.f,0.f,0.f,0.f}, ah1 = {0.f,0.f,0.f,0.f};
#pragma unroll
        for (int ks = 0; ks < KX; ks += 2) {
            bf16x8 a0 = *(const bf16x8*)(xb + arow * D_ + (ks    ) * 32 + kblk * 8);
            bf16x8 a1 = *(const bf16x8*)(xb + arow * D_ + (ks + 1) * 32 + kblk * 8);
            ax0 = __builtin_amdgcn_mfma_f32_16x16x32_bf16(a0, wxf[ks    ], ax0, 0, 0, 0);
            ax1 = __builtin_amdgcn_mfma_f32_16x16x32_bf16(a1, wxf[ks + 1], ax1, 0, 0, 0);
        }
#pragma unroll
        for (int ks = 0; ks < KH; ks += 2) {
            bf16x8 a0 = *(const bf16x8*)(hb + arow * H_ + (ks    ) * 32 + kblk * 8);
            bf16x8 a1 = *(const bf16x8*)(hb + arow * H_ + (ks + 1) * 32 + kblk * 8);
            ah0 = __builtin_amdgcn_mfma_f32_16x16x32_bf16(a0, whf[ks    ], ah0, 0, 0, 0);
            ah1 = __builtin_amdgcn_mfma_f32_16x16x32_bf16(a1, whf[ks + 1], ah1, 0, 0, 0);
        }
        f32x4 acc = (ax0 + ax1) + (ah0 + ah1);

        // D layout (m89): col = lane&15, row = (lane>>4)*4 + reg
#pragma unroll
        for (int r = 0; r < 4; ++r)
            gbuf[wv][kblk * 4 + r][c] = acc[r];
        __syncthreads();

        float gi = gbuf[wv][eb][0 * 4 + ej] + bi;
        float gf = gbuf[wv][eb][1 * 4 + ej] + bf;
        float gg = gbuf[wv][eb][2 * 4 + ej] + bg;
        float go = gbuf[wv][eb][3 * 4 + ej] + bo;

        float I = sigmoid_f(gi);
        float F = sigmoid_f(gf);
        float G = tanh_f(gg);
        float O = sigmoid_f(go);
        cstate = F * cstate + I * G;
        float hval = O * tanh_f(cstate);

        const int b = bw + eb;
        const int j = j0 + ej;
        y[(b * T_ + t) * H_ + j] = hval;
        h_buf[nxt * (B_ * H_) + b * H_ + j] = f2bf(hval);

        // convert x_{t+1} for next step (covered by the same barrier)
        if (t + 1 < T_ && tid < 128) {
            int m = wg * 128 + tid;
            int bb = m >> 9, d = m & 511;
            xb_buf[nxt * (B_ * D_) + m] = f2bf(x[(bb * T_ + (t + 1)) * D_ + d]);
        }

        // ---- end-of-step device barrier, phase t+2 ----
        __syncthreads();                       // drains all waves' vmem stores
        if (tid == 0) {
            __threadfence();                   // wb L2 -> L3 (release)
            __hip_atomic_store(&flags[wg], t + 2, __ATOMIC_RELAXED, __HIP_MEMORY_SCOPE_AGENT);
        }
        while (__hip_atomic_load(&flags[tid], __ATOMIC_RELAXED, __HIP_MEMORY_SCOPE_AGENT) < t + 2) {}
        __syncthreads();
        __threadfence();                       // inv L2 (acquire) before reading h_buf
    }
}

extern "C" void kernel_launch(void* const* d_in, const int* in_sizes, int n_in,
                              void* d_out, int out_size, void* d_ws, size_t ws_size,
                              hipStream_t stream)
{
    const float* x    = (const float*)d_in[0];
    const float* Wx   = (const float*)d_in[1];
    const float* Wh   = (const float*)d_in[2];
    const float* bias = (const float*)d_in[3];
    float* y = (float*)d_out;

    char* ws = (char*)d_ws;
    const size_t h_bytes  = (size_t)2 * B_ * H_ * sizeof(short);   // 256 KB
    const size_t xb_bytes = (size_t)2 * B_ * D_ * sizeof(short);   // 128 KB
    short* h_buf  = (short*)ws;
    short* xb_buf = (short*)(ws + h_bytes);
    int*   flags  = (int*)(ws + h_bytes + xb_bytes);

    // Re-init every call: h0 = 0, and flags MUST be zeroed (replays would
    // otherwise see stale phase values and race past the barrier).
    hipMemsetAsync(d_ws, 0, h_bytes + xb_bytes + NWG * sizeof(int), stream);

    lstm_persistent<<<dim3(NWG), dim3(256), 0, stream>>>(
        x, Wx, Wh, bias, y, h_buf, xb_buf, flags);
}

// Round 2
// 28995.337 us; speedup vs baseline: 1.2365x; 1.2365x over previous
//
#include <hip/hip_runtime.h>
#include <hip/hip_bf16.h>

#define B_  64
#define T_  1024
#define D_  512
#define H_  1024
#define G4H (4 * H_)
#define NWG 256
#define KX  16   // 512/32 K-steps for x part
#define KH  32   // 1024/32 K-steps for h part

typedef __attribute__((ext_vector_type(8))) short bf16x8;
typedef __attribute__((ext_vector_type(4))) float f32x4;

__device__ __forceinline__ short f2bf(float f) {
    union { float f; unsigned int u; } v;
    v.f = f;
    unsigned int r = v.u + 0x7FFFu + ((v.u >> 16) & 1u);  // RNE
    return (short)(r >> 16);
}

__device__ __forceinline__ float sigmoid_f(float x) {
    return 1.0f / (1.0f + __expf(-x));
}

__device__ __forceinline__ float tanh_f(float x) {
    float ax = fabsf(x);
    float e  = __expf(-2.0f * ax);
    float t  = (1.0f - e) / (1.0f + e);
    return copysignf(t, x);
}

// Two-hop device barrier, no atomic RMWs:
//   every WG:  flags[wg] = phase        (release)
//   WG0:       256 threads scan flags; tid0 stores gen = phase
//   other WGs: tid0 alone polls gen; rest of WG parked at __syncthreads
#define DEV_BARRIER(phase_)                                                        \
    do {                                                                           \
        __syncthreads();                                                           \
        if (tid == 0) {                                                            \
            __threadfence();  /* release: push h/xb stores to coherence point */   \
            __hip_atomic_store(&flags[wg], (phase_), __ATOMIC_RELAXED,             \
                               __HIP_MEMORY_SCOPE_AGENT);                          \
        }                                                                          \
        if (wg == 0) {                                                             \
            while (__hip_atomic_load(&flags[tid], __ATOMIC_RELAXED,                \
                                     __HIP_MEMORY_SCOPE_AGENT) < (phase_))         \
                __builtin_amdgcn_s_sleep(1);                                       \
            __syncthreads();                                                       \
            if (tid == 0) {                                                        \
                __threadfence();                                                   \
                __hip_atomic_store(gen, (phase_), __ATOMIC_RELAXED,                \
                                   __HIP_MEMORY_SCOPE_AGENT);                      \
            }                                                                      \
        } else if (tid == 0) {                                                     \
            while (__hip_atomic_load(gen, __ATOMIC_RELAXED,                        \
                                     __HIP_MEMORY_SCOPE_AGENT) < (phase_))         \
                __builtin_amdgcn_s_sleep(1);                                       \
        }                                                                          \
        __syncthreads();                                                           \
        __threadfence();  /* acquire: invalidate caches before reading h/xb */     \
    } while (0)

// Persistent cooperative LSTM scan.
// 256 WGs x 256 threads; WG wg owns hidden units j0=4*wg..j0+3 (16 gate cols).
// Wh/Wx slices live in registers as pre-packed bf16 MFMA B-fragments.
__global__ void __launch_bounds__(256, 1)
lstm_persistent(const float* __restrict__ x,     // [B,T,D]
                const float* __restrict__ Wx,    // [D,4H]
                const float* __restrict__ Wh,    // [H,4H]
                const float* __restrict__ bias,  // [4H] (i,f,g,o)
                float* __restrict__ y,           // [B,T,H]
                short* __restrict__ h_buf,       // ws: [2][B][H] bf16
                short* __restrict__ xb_buf,      // ws: [2][B][D] bf16
                int* flags,                      // ws: [NWG]
                int* gen)                        // ws: single int
{
    const int wg   = blockIdx.x;
    const int tid  = threadIdx.x;
    const int lane = tid & 63;
    const int wv   = tid >> 6;        // wave 0..3 -> batches wv*16..wv*16+15
    const int j0   = wg * 4;

    // ---- B-fragment lane mapping (mfma_f32_16x16x32_bf16):
    // lane&15 = B column (tile col c), lane>>4 = k-block, 8 contiguous k elems.
    const int c    = lane & 15;
    const int gate = c >> 2;          // 0..3 = i,f,g,o
    const int hh   = c & 3;           // hidden unit within WG
    const int gcol = gate * H_ + j0 + hh;
    const int kblk = lane >> 4;

    // ---- prologue: pack Wx/Wh slices into register-resident bf16 fragments
    bf16x8 wxf[KX];
#pragma unroll
    for (int ks = 0; ks < KX; ++ks) {
        bf16x8 tf;
#pragma unroll
        for (int e = 0; e < 8; ++e) {
            int k = ks * 32 + kblk * 8 + e;
            tf[e] = f2bf(Wx[k * G4H + gcol]);
        }
        wxf[ks] = tf;
    }
    bf16x8 whf[KH];
#pragma unroll
    for (int ks = 0; ks < KH; ++ks) {
        bf16x8 tf;
#pragma unroll
        for (int e = 0; e < 8; ++e) {
            int k = ks * 32 + kblk * 8 + e;
            tf[e] = f2bf(Wh[k * G4H + gcol]);
        }
        whf[ks] = tf;
    }

    // ---- epilogue lane mapping: 4 consecutive lanes own 4 consecutive j
    // -> coalesced 16B y-stores and 8B h-stores
    const int eb = lane >> 2;         // batch within wave's 16
    const int ej = lane & 3;          // hidden unit within WG
    const float bi = bias[0 * H_ + j0 + ej];
    const float bf = bias[1 * H_ + j0 + ej];
    const float bg = bias[2 * H_ + j0 + ej];
    const float bo = bias[3 * H_ + j0 + ej];

    float cstate = 0.0f;              // c for (batch bw+eb, hidden j0+ej)

    __shared__ float gbuf[4][16][17]; // +1 pad: epilogue reads <=2-way banks

    const int bw   = wv * 16;
    const int arow = bw + (lane & 15);   // A-fragment row = batch

    // ---- prologue: convert x_0 -> xb_buf[0] (each WG converts 128 elems)
    if (tid < 128) {
        int m = wg * 128 + tid;          // m in [0, B*D)
        int b = m >> 9, d = m & 511;
        xb_buf[m] = f2bf(x[(b * T_ + 0) * D_ + d]);
    }
    DEV_BARRIER(1);   // h_buf[0] zeroed by host-side memset

#pragma unroll 1
    for (int t = 0; t < T_; ++t) {
        const int cur = t & 1;
        const int nxt = cur ^ 1;
        const short* hb = h_buf  + cur * (B_ * H_);
        const short* xb = xb_buf + cur * (B_ * D_);

        // 4 independent accumulator chains to break MFMA dep latency
        f32x4 ax0 = {0.f,0.f,0.f,0.f}, ax1 = {0.f,0.f,0.f,0.f};
        f32x4 ah0 = {0.f,0.f,0.f,0.f}, ah1 = {0.f,0.f,0.f,0.f};
#pragma unroll
        for (int ks = 0; ks < KX; ks += 2) {
            bf16x8 a0 = *(const bf16x8*)(xb + arow * D_ + (ks    ) * 32 + kblk * 8);
            bf16x8 a1 = *(const bf16x8*)(xb + arow * D_ + (ks + 1) * 32 + kblk * 8);
            ax0 = __builtin_amdgcn_mfma_f32_16x16x32_bf16(a0, wxf[ks    ], ax0, 0, 0, 0);
            ax1 = __builtin_amdgcn_mfma_f32_16x16x32_bf16(a1, wxf[ks + 1], ax1, 0, 0, 0);
        }
#pragma unroll
        for (int ks = 0; ks < KH; ks += 2) {
            bf16x8 a0 = *(const bf16x8*)(hb + arow * H_ + (ks    ) * 32 + kblk * 8);
            bf16x8 a1 = *(const bf16x8*)(hb + arow * H_ + (ks + 1) * 32 + kblk * 8);
            ah0 = __builtin_amdgcn_mfma_f32_16x16x32_bf16(a0, whf[ks    ], ah0, 0, 0, 0);
            ah1 = __builtin_amdgcn_mfma_f32_16x16x32_bf16(a1, whf[ks + 1], ah1, 0, 0, 0);
        }
        f32x4 acc = (ax0 + ax1) + (ah0 + ah1);

        // D layout (m89): col = lane&15, row = (lane>>4)*4 + reg
#pragma unroll
        for (int r = 0; r < 4; ++r)
            gbuf[wv][kblk * 4 + r][c] = acc[r];
        __syncthreads();

        float gi = gbuf[wv][eb][0 * 4 + ej] + bi;
        float gf = gbuf[wv][eb][1 * 4 + ej] + bf;
        float gg = gbuf[wv][eb][2 * 4 + ej] + bg;
        float go = gbuf[wv][eb][3 * 4 + ej] + bo;

        float I = sigmoid_f(gi);
        float F = sigmoid_f(gf);
        float G = tanh_f(gg);
        float O = sigmoid_f(go);
        cstate = F * cstate + I * G;
        float hval = O * tanh_f(cstate);

        const int b = bw + eb;
        const int j = j0 + ej;
        y[(b * T_ + t) * H_ + j] = hval;                     // 16B/4-lane chunk
        h_buf[nxt * (B_ * H_) + b * H_ + j] = f2bf(hval);    // 8B/4-lane chunk

        // convert x_{t+1} for next step (covered by the same barrier)
        if (t + 1 < T_ && tid < 128) {
            int m = wg * 128 + tid;
            int bb = m >> 9, d = m & 511;
            xb_buf[nxt * (B_ * D_) + m] = f2bf(x[(bb * T_ + (t + 1)) * D_ + d]);
        }

        DEV_BARRIER(t + 2);
    }
}

extern "C" void kernel_launch(void* const* d_in, const int* in_sizes, int n_in,
                              void* d_out, int out_size, void* d_ws, size_t ws_size,
                              hipStream_t stream)
{
    const float* x    = (const float*)d_in[0];
    const float* Wx   = (const float*)d_in[1];
    const float* Wh   = (const float*)d_in[2];
    const float* bias = (const float*)d_in[3];
    float* y = (float*)d_out;

    char* ws = (char*)d_ws;
    const size_t h_bytes  = (size_t)2 * B_ * H_ * sizeof(short);   // 256 KB
    const size_t xb_bytes = (size_t)2 * B_ * D_ * sizeof(short);   // 128 KB
    short* h_buf  = (short*)ws;
    short* xb_buf = (short*)(ws + h_bytes);
    int*   flags  = (int*)(ws + h_bytes + xb_bytes);
    int*   gen    = (int*)(ws + h_bytes + xb_bytes + 2048);

    // Re-init every call: h0 = 0; flags/gen MUST be zeroed (stale phase values
    // from a prior replay would let pollers race past the barrier).
    hipMemsetAsync(d_ws, 0, h_bytes + xb_bytes + 4096, stream);

    lstm_persistent<<<dim3(NWG), dim3(256), 0, stream>>>(
        x, Wx, Wh, bias, y, h_buf, xb_buf, flags, gen);
}

// Round 3
// 14491.251 us; speedup vs baseline: 2.4741x; 2.0009x over previous
//
#include <hip/hip_runtime.h>
#include <hip/hip_bf16.h>

#define B_  64
#define T_  1024
#define D_  512
#define H_  1024
#define G4H (4 * H_)
#define NWG 256
#define KX  16           // 512/32 K-steps for x part
#define KH  32           // 1024/32 K-steps for h part
#define FLAG_STRIDE 16   // ints -> 64B-separated flags

typedef __attribute__((ext_vector_type(8))) short bf16x8;
typedef __attribute__((ext_vector_type(4))) float f32x4;

__device__ __forceinline__ short f2bf(float f) {
    union { float f; unsigned int u; } v; v.f = f;
    unsigned int r = v.u + 0x7FFFu + ((v.u >> 16) & 1u);  // RNE
    return (short)(r >> 16);
}
__device__ __forceinline__ float sigmoid_f(float x) { return 1.0f / (1.0f + __expf(-x)); }
__device__ __forceinline__ float tanh_f(float x) {
    float ax = fabsf(x);
    float e  = __expf(-2.0f * ax);
    float t  = (1.0f - e) / (1.0f + e);
    return copysignf(t, x);
}

// 16B device-coherent load (2 x 8B agent-scope relaxed atomics -> sc-flagged
// global_load_dwordx2, serviced at the coherence point; NO buffer_inv needed).
__device__ __forceinline__ bf16x8 load_h16(const short* p) {
    union { bf16x8 v; unsigned long long q[2]; } u;
    u.q[0] = __hip_atomic_load((const unsigned long long*)p,
                               __ATOMIC_RELAXED, __HIP_MEMORY_SCOPE_AGENT);
    u.q[1] = __hip_atomic_load((const unsigned long long*)p + 1,
                               __ATOMIC_RELAXED, __HIP_MEMORY_SCOPE_AGENT);
    return u.v;
}

// Persistent cooperative LSTM scan, fence-free coherence:
//  - h ping-pongs through IC via agent-scope (sc-flagged) atomics
//  - x read as f32 directly (read-only, cacheable) -> x-MFMA overlaps barrier
//  - release ordering: __syncthreads drains vmcnt(0) before tid0's flag store
__global__ void __launch_bounds__(256, 1)
lstm_persistent(const float* __restrict__ x,     // [B,T,D]
                const float* __restrict__ Wx,    // [D,4H]
                const float* __restrict__ Wh,    // [H,4H]
                const float* __restrict__ bias,  // [4H] (i,f,g,o)
                float* __restrict__ y,           // [B,T,H]
                short* __restrict__ h_buf,       // ws: [2][B][H] bf16
                int* __restrict__ flags,         // ws: [NWG*FLAG_STRIDE]
                int* __restrict__ gen)           // ws: single int
{
    const int wg   = blockIdx.x;
    const int tid  = threadIdx.x;
    const int lane = tid & 63;
    const int wv   = tid >> 6;        // wave 0..3 -> batches wv*16..wv*16+15
    const int j0   = wg * 4;

    // B-fragment lane mapping (mfma_f32_16x16x32_bf16):
    // lane&15 = B column, lane>>4 = k-block (8 contiguous k elems).
    const int c    = lane & 15;
    const int gate = c >> 2;          // 0..3 = i,f,g,o
    const int hh   = c & 3;
    const int gcol = gate * H_ + j0 + hh;
    const int kblk = lane >> 4;

    // ---- prologue: pack Wx/Wh slices into register-resident bf16 B-frags
    bf16x8 wxf[KX];
#pragma unroll
    for (int ks = 0; ks < KX; ++ks) {
        bf16x8 tf;
#pragma unroll
        for (int e = 0; e < 8; ++e)
            tf[e] = f2bf(Wx[(ks * 32 + kblk * 8 + e) * G4H + gcol]);
        wxf[ks] = tf;
    }
    bf16x8 whf[KH];
#pragma unroll
    for (int ks = 0; ks < KH; ++ks) {
        bf16x8 tf;
#pragma unroll
        for (int e = 0; e < 8; ++e)
            tf[e] = f2bf(Wh[(ks * 32 + kblk * 8 + e) * G4H + gcol]);
        whf[ks] = tf;
    }

    // epilogue lane mapping: 4 consecutive lanes = 4 consecutive j
    const int eb = lane >> 2;
    const int ej = lane & 3;
    const float bi = bias[0 * H_ + j0 + ej];
    const float bf = bias[1 * H_ + j0 + ej];
    const float bg = bias[2 * H_ + j0 + ej];
    const float bo = bias[3 * H_ + j0 + ej];

    float cstate = 0.0f;

    __shared__ float gbuf[4][16][17];

    const int bw   = wv * 16;
    const int arow = bw + (lane & 15);            // A-row = batch
    const float* xbase = x + (size_t)arow * T_ * D_ + kblk * 8;

    // No entry barrier needed: h_buf[0] + flags + gen zeroed host-side,
    // memset is stream-ordered before this kernel.

#pragma unroll 1
    for (int t = 0; t < T_; ++t) {
        // ---- x-part: dependency-free, overlaps other WGs finishing t-1 ----
        f32x4 ax0 = {0.f,0.f,0.f,0.f}, ax1 = {0.f,0.f,0.f,0.f};
        const float* xr = xbase + (size_t)t * D_;
#pragma unroll
        for (int ks = 0; ks < KX; ks += 2) {
            const float* p0 = xr + ks * 32;
            const float* p1 = p0 + 32;
            bf16x8 a0, a1;
#pragma unroll
            for (int e = 0; e < 8; ++e) { a0[e] = f2bf(p0[e]); a1[e] = f2bf(p1[e]); }
            ax0 = __builtin_amdgcn_mfma_f32_16x16x32_bf16(a0, wxf[ks    ], ax0, 0, 0, 0);
            ax1 = __builtin_amdgcn_mfma_f32_16x16x32_bf16(a1, wxf[ks + 1], ax1, 0, 0, 0);
        }

        // ---- wait for phase t (h_t visible at coherence point) ----
        if (t > 0) {
            if (wg == 0) {
                while (__hip_atomic_load(&flags[tid * FLAG_STRIDE],
                                         __ATOMIC_RELAXED, __HIP_MEMORY_SCOPE_AGENT) < t)
                    __builtin_amdgcn_s_sleep(2);
                __syncthreads();
                if (tid == 0)
                    __hip_atomic_store(gen, t, __ATOMIC_RELAXED, __HIP_MEMORY_SCOPE_AGENT);
            } else {
                if (tid == 0)
                    while (__hip_atomic_load(gen, __ATOMIC_RELAXED,
                                             __HIP_MEMORY_SCOPE_AGENT) < t)
                        __builtin_amdgcn_s_sleep(2);
                __syncthreads();
            }
        }

        // ---- h-part: device-coherent loads of h_t ----
        const short* hb = h_buf + (t & 1) * (B_ * H_) + arow * H_ + kblk * 8;
        f32x4 ah0 = {0.f,0.f,0.f,0.f}, ah1 = {0.f,0.f,0.f,0.f};
#pragma unroll
        for (int ks = 0; ks < KH; ks += 2) {
            bf16x8 a0 = load_h16(hb + ks * 32);
            bf16x8 a1 = load_h16(hb + ks * 32 + 32);
            ah0 = __builtin_amdgcn_mfma_f32_16x16x32_bf16(a0, whf[ks    ], ah0, 0, 0, 0);
            ah1 = __builtin_amdgcn_mfma_f32_16x16x32_bf16(a1, whf[ks + 1], ah1, 0, 0, 0);
        }
        f32x4 acc = (ax0 + ax1) + (ah0 + ah1);

        // D layout (m89): col = lane&15, row = (lane>>4)*4 + reg
#pragma unroll
        for (int r = 0; r < 4; ++r)
            gbuf[wv][kblk * 4 + r][c] = acc[r];
        __syncthreads();

        float gi = gbuf[wv][eb][0 * 4 + ej] + bi;
        float gf = gbuf[wv][eb][1 * 4 + ej] + bf;
        float gg = gbuf[wv][eb][2 * 4 + ej] + bg;
        float go = gbuf[wv][eb][3 * 4 + ej] + bo;

        float I = sigmoid_f(gi);
        float F = sigmoid_f(gf);
        float G = tanh_f(gg);
        float O = sigmoid_f(go);
        cstate = F * cstate + I * G;
        float hval = O * tanh_f(cstate);

        const int b = bw + eb;
        const int j = j0 + ej;
        y[(size_t)(b * T_ + t) * H_ + j] = hval;   // coalesced 16B / 4 lanes

        // packed 4B agent-scope h store (pair lanes ej, ej^1)
        unsigned int mybf  = (unsigned int)(unsigned short)f2bf(hval);
        unsigned int other = (unsigned int)__shfl_xor((int)mybf, 1, 64);
        if ((ej & 1) == 0) {
            unsigned int packed = mybf | (other << 16);
            unsigned int* hp = (unsigned int*)(h_buf + ((t + 1) & 1) * (B_ * H_) + b * H_ + j);
            __hip_atomic_store(hp, packed, __ATOMIC_RELAXED, __HIP_MEMORY_SCOPE_AGENT);
        }

        // ---- signal phase t+1 ----
        // __syncthreads waits vmcnt(0) in every wave -> all sc-stores acked at
        // the coherence point before tid0's flag store issues. No fence needed.
        __syncthreads();
        if (tid == 0)
            __hip_atomic_store(&flags[wg * FLAG_STRIDE], t + 1,
                               __ATOMIC_RELAXED, __HIP_MEMORY_SCOPE_AGENT);
    }
}

extern "C" void kernel_launch(void* const* d_in, const int* in_sizes, int n_in,
                              void* d_out, int out_size, void* d_ws, size_t ws_size,
                              hipStream_t stream)
{
    const float* x    = (const float*)d_in[0];
    const float* Wx   = (const float*)d_in[1];
    const float* Wh   = (const float*)d_in[2];
    const float* bias = (const float*)d_in[3];
    float* y = (float*)d_out;

    char* ws = (char*)d_ws;
    const size_t h_bytes    = (size_t)2 * B_ * H_ * sizeof(short);      // 256 KB
    const size_t flag_bytes = (size_t)NWG * FLAG_STRIDE * sizeof(int);  // 16 KB
    short* h_buf = (short*)ws;
    int*   flags = (int*)(ws + h_bytes);
    int*   gen   = (int*)(ws + h_bytes + flag_bytes);

    // Re-init every call: h0 = 0; flags/gen MUST be zeroed (stale phases from
    // a prior replay would let pollers race past the barrier).
    hipMemsetAsync(d_ws, 0, h_bytes + flag_bytes + 64, stream);

    lstm_persistent<<<dim3(NWG), dim3(256), 0, stream>>>(
        x, Wx, Wh, bias, y, h_buf, flags, gen);
}

// Round 4
// 6309.618 us; speedup vs baseline: 5.6823x; 2.2967x over previous
//
#include <hip/hip_runtime.h>
#include <hip/hip_bf16.h>

#define B_  64
#define T_  1024
#define D_  512
#define H_  1024
#define G4H (4 * H_)
#define NWG 256
#define FLAG_STRIDE 16   // ints -> 64B-separated flags

typedef __attribute__((ext_vector_type(8))) short bf16x8;
typedef __attribute__((ext_vector_type(4))) float f32x4;

__device__ __forceinline__ short f2bf(float f) {
    union { float f; unsigned int u; } v; v.f = f;
    unsigned int r = v.u + 0x7FFFu + ((v.u >> 16) & 1u);  // RNE
    return (short)(r >> 16);
}
__device__ __forceinline__ float sigmoid_f(float x) { return 1.0f / (1.0f + __expf(-x)); }
__device__ __forceinline__ float tanh_f(float x) {
    float ax = fabsf(x);
    float e  = __expf(-2.0f * ax);
    float t  = (1.0f - e) / (1.0f + e);
    return copysignf(t, x);
}

// 16B device-coherent load (2 x 8B agent-scope relaxed atomics -> sc-flagged
// loads serviced at the coherence point; no cache-walk fences needed).
__device__ __forceinline__ bf16x8 load_h16(const short* p) {
    union { bf16x8 v; unsigned long long q[2]; } u;
    u.q[0] = __hip_atomic_load((const unsigned long long*)p,
                               __ATOMIC_RELAXED, __HIP_MEMORY_SCOPE_AGENT);
    u.q[1] = __hip_atomic_load((const unsigned long long*)p + 1,
                               __ATOMIC_RELAXED, __HIP_MEMORY_SCOPE_AGENT);
    return u.v;
}

// Persistent cooperative LSTM scan, round 4:
//  WG = (batch-tile 16) x (hidden-tile 16); 4 waves split K (h: 256/wave,
//  x: 128/wave), partials reduced through LDS. Per-lane coherent h loads:
//  8 x 16B, batch-issued -> one IC round-trip instead of a 64-load chain.
__global__ void __launch_bounds__(256, 1)
lstm_persistent(const float* __restrict__ x,     // [B,T,D]
                const float* __restrict__ Wx,    // [D,4H]
                const float* __restrict__ Wh,    // [H,4H]
                const float* __restrict__ bias,  // [4H] (i,f,g,o)
                float* __restrict__ y,           // [B,T,H]
                short* __restrict__ h_buf,       // ws: [2][B][H] bf16
                int* __restrict__ flags,         // ws: [NWG*FLAG_STRIDE]
                int* __restrict__ gen)           // ws: single int
{
    const int wg   = blockIdx.x;
    const int tid  = threadIdx.x;
    const int lane = tid & 63;
    const int wv   = tid >> 6;
    // XCD-chunked bijection (grid 256 = 8 XCDs * 32): contiguous work per XCD
    const int wgs  = ((wg & 7) << 5) | (wg >> 3);
    const int bt   = wgs >> 6;          // batch tile 0..3 (16 batches each)
    const int j0   = (wgs & 63) * 16;   // hidden tile base (16 units)

    const int c    = lane & 15;         // A-row (batch) / B-col within tile
    const int kblk = lane >> 4;         // k-block (8 contiguous k)
    const int b_a  = bt * 16 + c;       // global batch for A-frags
    const int kh0  = wv * 256;          // this wave's K-slice of H
    const int kx0  = wv * 128;          // this wave's K-slice of D

    // ---- prologue: pack weight slices into register-resident B-frags.
    // whf[g][ks]: gate g, K = kh0 + ks*32 + kblk*8 .. +8, col = j0 + c
    bf16x8 whf[4][8];
#pragma unroll
    for (int g = 0; g < 4; ++g)
#pragma unroll
        for (int ks = 0; ks < 8; ++ks) {
            bf16x8 tf;
#pragma unroll
            for (int e = 0; e < 8; ++e)
                tf[e] = f2bf(Wh[(size_t)(kh0 + ks * 32 + kblk * 8 + e) * G4H
                                + g * H_ + j0 + c]);
            whf[g][ks] = tf;
        }
    bf16x8 wxf[4][4];
#pragma unroll
    for (int g = 0; g < 4; ++g)
#pragma unroll
        for (int ks = 0; ks < 4; ++ks) {
            bf16x8 tf;
#pragma unroll
            for (int e = 0; e < 8; ++e)
                tf[e] = f2bf(Wx[(size_t)(kx0 + ks * 32 + kblk * 8 + e) * G4H
                                + g * H_ + j0 + c]);
            wxf[g][ks] = tf;
        }

    // ---- epilogue mapping: thread -> (batch eb, hidden ej), one (b,j) each
    const int eb = tid >> 4;            // 0..15
    const int ej = tid & 15;            // 0..15
    const float bi = bias[0 * H_ + j0 + ej];
    const float bf = bias[1 * H_ + j0 + ej];
    const float bg = bias[2 * H_ + j0 + ej];
    const float bo = bias[3 * H_ + j0 + ej];
    const int b_glob = bt * 16 + eb;
    const int j_glob = j0 + ej;

    float cstate = 0.0f;

    // per-wave partial gate tiles: [wave][batch-row][64 cols + pad(3)]
    __shared__ float gbuf[4][16][67];

#pragma unroll 1
    for (int t = 0; t < T_; ++t) {
        f32x4 acc[4] = {{0.f,0.f,0.f,0.f},{0.f,0.f,0.f,0.f},
                        {0.f,0.f,0.f,0.f},{0.f,0.f,0.f,0.f}};

        // ---- x-part (dependency-free; overlaps other WGs finishing t-1) ----
        const float* xr = x + ((size_t)b_a * T_ + t) * D_ + kx0 + kblk * 8;
#pragma unroll
        for (int ks = 0; ks < 4; ++ks) {
            f32x4 lo = *(const f32x4*)(xr + ks * 32);
            f32x4 hi = *(const f32x4*)(xr + ks * 32 + 4);
            bf16x8 xa;
#pragma unroll
            for (int e = 0; e < 4; ++e) { xa[e] = f2bf(lo[e]); xa[e + 4] = f2bf(hi[e]); }
#pragma unroll
            for (int g = 0; g < 4; ++g)
                acc[g] = __builtin_amdgcn_mfma_f32_16x16x32_bf16(xa, wxf[g][ks], acc[g], 0, 0, 0);
        }

        // ---- wait for phase t (h_t visible at coherence point) ----
        if (t > 0) {
            if (wg == 0) {
                while (__hip_atomic_load(&flags[tid * FLAG_STRIDE],
                                         __ATOMIC_RELAXED, __HIP_MEMORY_SCOPE_AGENT) < t)
                    __builtin_amdgcn_s_sleep(1);
                __syncthreads();
                if (tid == 0)
                    __hip_atomic_store(gen, t, __ATOMIC_RELAXED, __HIP_MEMORY_SCOPE_AGENT);
            } else {
                if (tid == 0)
                    while (__hip_atomic_load(gen, __ATOMIC_RELAXED,
                                             __HIP_MEMORY_SCOPE_AGENT) < t)
                        __builtin_amdgcn_s_sleep(1);
                __syncthreads();
            }
        }

        // ---- h-part: 8 x 16B coherent loads, ALL issued before consumers ----
        const short* hb = h_buf + (t & 1) * (B_ * H_) + (size_t)b_a * H_ + kh0 + kblk * 8;
        bf16x8 ha[8];
#pragma unroll
        for (int ks = 0; ks < 8; ++ks)
            ha[ks] = load_h16(hb + ks * 32);
#pragma unroll
        for (int ks = 0; ks < 8; ++ks)
#pragma unroll
            for (int g = 0; g < 4; ++g)
                acc[g] = __builtin_amdgcn_mfma_f32_16x16x32_bf16(ha[ks], whf[g][ks], acc[g], 0, 0, 0);

        // ---- partials to LDS (D layout: col = lane&15, row = kblk*4 + r) ----
#pragma unroll
        for (int g = 0; g < 4; ++g)
#pragma unroll
            for (int r = 0; r < 4; ++r)
                gbuf[wv][kblk * 4 + r][g * 16 + c] = acc[g][r];
        __syncthreads();

        // ---- epilogue: sum 4 wave-partials, gates, state update ----
        float gi = ((gbuf[0][eb][ 0 + ej] + gbuf[1][eb][ 0 + ej])
                  + (gbuf[2][eb][ 0 + ej] + gbuf[3][eb][ 0 + ej])) + bi;
        float gf = ((gbuf[0][eb][16 + ej] + gbuf[1][eb][16 + ej])
                  + (gbuf[2][eb][16 + ej] + gbuf[3][eb][16 + ej])) + bf;
        float gg = ((gbuf[0][eb][32 + ej] + gbuf[1][eb][32 + ej])
                  + (gbuf[2][eb][32 + ej] + gbuf[3][eb][32 + ej])) + bg;
        float go = ((gbuf[0][eb][48 + ej] + gbuf[1][eb][48 + ej])
                  + (gbuf[2][eb][48 + ej] + gbuf[3][eb][48 + ej])) + bo;

        float I = sigmoid_f(gi);
        float F = sigmoid_f(gf);
        float G = tanh_f(gg);
        float O = sigmoid_f(go);
        cstate = F * cstate + I * G;
        float hval = O * tanh_f(cstate);

        y[((size_t)b_glob * T_ + t) * H_ + j_glob] = hval;   // 64B / 16 lanes

        // packed 4B agent-scope h store (lane pairs ej, ej^1)
        unsigned int mybf  = (unsigned int)(unsigned short)f2bf(hval);
        unsigned int other = (unsigned int)__shfl_xor((int)mybf, 1, 64);
        if ((ej & 1) == 0) {
            unsigned int packed = mybf | (other << 16);
            unsigned int* hp = (unsigned int*)(h_buf + ((t + 1) & 1) * (B_ * H_)
                                               + (size_t)b_glob * H_ + j_glob);
            __hip_atomic_store(hp, packed, __ATOMIC_RELAXED, __HIP_MEMORY_SCOPE_AGENT);
        }

        // ---- signal phase t+1 ----
        // __syncthreads drains vmcnt(0) in every wave -> all sc-stores acked
        // at the coherence point before tid0's flag store issues.
        __syncthreads();
        if (tid == 0)
            __hip_atomic_store(&flags[wg * FLAG_STRIDE], t + 1,
                               __ATOMIC_RELAXED, __HIP_MEMORY_SCOPE_AGENT);
    }
}

extern "C" void kernel_launch(void* const* d_in, const int* in_sizes, int n_in,
                              void* d_out, int out_size, void* d_ws, size_t ws_size,
                              hipStream_t stream)
{
    const float* x    = (const float*)d_in[0];
    const float* Wx   = (const float*)d_in[1];
    const float* Wh   = (const float*)d_in[2];
    const float* bias = (const float*)d_in[3];
    float* y = (float*)d_out;

    char* ws = (char*)d_ws;
    const size_t h_bytes    = (size_t)2 * B_ * H_ * sizeof(short);      // 256 KB
    const size_t flag_bytes = (size_t)NWG * FLAG_STRIDE * sizeof(int);  // 16 KB
    short* h_buf = (short*)ws;
    int*   flags = (int*)(ws + h_bytes);
    int*   gen   = (int*)(ws + h_bytes + flag_bytes);

    // Re-init every call: h0 = 0; flags/gen MUST be zeroed (stale phases from
    // a prior replay would let pollers race past the barrier).
    hipMemsetAsync(d_ws, 0, h_bytes + flag_bytes + 64, stream);

    lstm_persistent<<<dim3(NWG), dim3(256), 0, stream>>>(
        x, Wx, Wh, bias, y, h_buf, flags, gen);
}

// Round 5
// 4815.287 us; speedup vs baseline: 7.4457x; 1.3103x over previous
//
#include <hip/hip_runtime.h>
#include <hip/hip_bf16.h>

#define B_  64
#define T_  1024
#define D_  512
#define H_  1024
#define G4H (4 * H_)
#define NWG 256
#define FLAG_STRIDE 16   // ints -> 64B-separated flags

typedef __attribute__((ext_vector_type(8))) short bf16x8;
typedef __attribute__((ext_vector_type(4))) float f32x4;

__device__ __forceinline__ short f2bf(float f) {
    union { float f; unsigned int u; } v; v.f = f;
    unsigned int r = v.u + 0x7FFFu + ((v.u >> 16) & 1u);  // RNE
    return (short)(r >> 16);
}
__device__ __forceinline__ float sigmoid_f(float x) { return 1.0f / (1.0f + __expf(-x)); }
__device__ __forceinline__ float tanh_f(float x) {
    float ax = fabsf(x);
    float e  = __expf(-2.0f * ax);
    return copysignf((1.0f - e) / (1.0f + e), x);
}

// 16B device-coherent load (2 x 8B agent-scope relaxed atomics -> sc-flagged
// loads serviced at the coherence point; no cache-walk fences needed).
__device__ __forceinline__ bf16x8 load_h16(const short* p) {
    union { bf16x8 v; unsigned long long q[2]; } u;
    u.q[0] = __hip_atomic_load((const unsigned long long*)p,
                               __ATOMIC_RELAXED, __HIP_MEMORY_SCOPE_AGENT);
    u.q[1] = __hip_atomic_load((const unsigned long long*)p + 1,
                               __ATOMIC_RELAXED, __HIP_MEMORY_SCOPE_AGENT);
    return u.v;
}

// R5: (1) h-weights LDS-resident (R4's VGPR_Count=132 proved the compiler was
// re-loading+re-converting 192 VGPRs of weights EVERY step, ~1us/step VALU);
// (2) per-batch-group one-hop barrier (4 independent 64-WG chains; no WG0
// aggregator serializing its x-phase into every step); (3) x loads issued
// before the poll so HBM latency hides under barrier wait.
__global__ void __launch_bounds__(256, 1)
lstm_persistent(const float* __restrict__ x,     // [B,T,D]
                const float* __restrict__ Wx,    // [D,4H]
                const float* __restrict__ Wh,    // [H,4H]
                const float* __restrict__ bias,  // [4H] (i,f,g,o)
                float* __restrict__ y,           // [B,T,H]
                short* __restrict__ h_buf,       // ws: [2][B][H] bf16
                int* __restrict__ flags)         // ws: [NWG*FLAG_STRIDE]
{
    const int wg   = blockIdx.x;
    const int tid  = threadIdx.x;
    const int lane = tid & 63;
    const int wv   = tid >> 6;
    // Round-robin dispatch puts wg on XCD wg&7 -> group bt = XCD pair
    // (group's 64 WGs land on 2 XCDs: x/h L2 locality, decoupled barriers).
    const int bt   = (wg >> 1) & 3;               // batch tile 0..3
    const int jt   = ((wg & 1) << 5) | (wg >> 3); // hidden tile 0..63
    const int j0   = jt * 16;

    const int c    = lane & 15;         // A-row (batch) / B-col within tile
    const int kblk = lane >> 4;         // k-block (8 contiguous k)
    const int b_a  = bt * 16 + c;       // global batch for A-frags
    const int kh0  = wv * 256;          // wave's K-slice of H
    const int kx0  = wv * 128;          // wave's K-slice of D

    __shared__ bf16x8 hw[4][4][8][64];  // 128 KB: [wv][gate][ks][lane]
    __shared__ float  gbuf[4][16][67];  // 17 KB partial-gate tiles

    // ---- prologue: h-weights -> LDS, each thread fills its own slot
    // (written and read by the same thread -> no barrier needed)
#pragma unroll
    for (int g = 0; g < 4; ++g)
#pragma unroll
        for (int ks = 0; ks < 8; ++ks) {
            bf16x8 tf;
#pragma unroll
            for (int e = 0; e < 8; ++e)
                tf[e] = f2bf(Wh[(size_t)(kh0 + ks * 32 + kblk * 8 + e) * G4H
                                + g * H_ + j0 + c]);
            hw[wv][g][ks][lane] = tf;
        }

    // ---- x-weights -> registers (64 VGPRs), pinned vs rematerialization
    bf16x8 wxf[4][4];
#pragma unroll
    for (int g = 0; g < 4; ++g)
#pragma unroll
        for (int ks = 0; ks < 4; ++ks) {
            bf16x8 tf;
#pragma unroll
            for (int e = 0; e < 8; ++e)
                tf[e] = f2bf(Wx[(size_t)(kx0 + ks * 32 + kblk * 8 + e) * G4H
                                + g * H_ + j0 + c]);
            wxf[g][ks] = tf;
        }
#pragma unroll
    for (int g = 0; g < 4; ++g)
#pragma unroll
        for (int ks = 0; ks < 4; ++ks)
            asm volatile("" : "+v"(wxf[g][ks]));   // opaque: cannot re-load

    // ---- epilogue mapping: thread -> one (batch eb, hidden ej)
    const int eb = tid >> 4;
    const int ej = tid & 15;
    const float bi  = bias[0 * H_ + j0 + ej];
    const float bfv = bias[1 * H_ + j0 + ej];
    const float bg  = bias[2 * H_ + j0 + ej];
    const float bo  = bias[3 * H_ + j0 + ej];
    const int b_glob = bt * 16 + eb;
    const int j_glob = j0 + ej;

    float cstate = 0.0f;
    const int* fpoll = flags + ((bt << 6) | lane) * FLAG_STRIDE; // group flags

#pragma unroll 1
    for (int t = 0; t < T_; ++t) {
        // (1) issue x loads early: in flight across the barrier wait
        const float* xr = x + ((size_t)b_a * T_ + t) * D_ + kx0 + kblk * 8;
        f32x4 xl[4], xh[4];
#pragma unroll
        for (int ks = 0; ks < 4; ++ks) {
            xl[ks] = *(const f32x4*)(xr + ks * 32);
            xh[ks] = *(const f32x4*)(xr + ks * 32 + 4);
        }

        // (2) one-hop group barrier: wave0's 64 lanes poll the 64 group flags;
        // divergent spin reconverges when every lane has seen its flag >= t.
        if (t > 0) {
            if (wv == 0)
                while (__hip_atomic_load(fpoll, __ATOMIC_RELAXED,
                                         __HIP_MEMORY_SCOPE_AGENT) < t) {}
            __syncthreads();
        }

        // (3) h loads: 8 x 16B coherent, batch-issued (one IC round-trip)
        const short* hb = h_buf + (t & 1) * (B_ * H_)
                        + (size_t)b_a * H_ + kh0 + kblk * 8;
        bf16x8 ha[8];
#pragma unroll
        for (int ks = 0; ks < 8; ++ks)
            ha[ks] = load_h16(hb + ks * 32);

        // (4) x MFMAs (xl/xh arrived during the poll)
        f32x4 acc[4] = {{0.f,0.f,0.f,0.f},{0.f,0.f,0.f,0.f},
                        {0.f,0.f,0.f,0.f},{0.f,0.f,0.f,0.f}};
#pragma unroll
        for (int ks = 0; ks < 4; ++ks) {
            bf16x8 xa;
#pragma unroll
            for (int e = 0; e < 4; ++e) { xa[e] = f2bf(xl[ks][e]); xa[e+4] = f2bf(xh[ks][e]); }
#pragma unroll
            for (int g = 0; g < 4; ++g)
                acc[g] = __builtin_amdgcn_mfma_f32_16x16x32_bf16(xa, wxf[g][ks], acc[g], 0, 0, 0);
        }

        // (5) h MFMAs, weights streamed from LDS (lane-contiguous b128 reads)
#pragma unroll
        for (int ks = 0; ks < 8; ++ks) {
            bf16x8 w0 = hw[wv][0][ks][lane];
            bf16x8 w1 = hw[wv][1][ks][lane];
            bf16x8 w2 = hw[wv][2][ks][lane];
            bf16x8 w3 = hw[wv][3][ks][lane];
            acc[0] = __builtin_amdgcn_mfma_f32_16x16x32_bf16(ha[ks], w0, acc[0], 0, 0, 0);
            acc[1] = __builtin_amdgcn_mfma_f32_16x16x32_bf16(ha[ks], w1, acc[1], 0, 0, 0);
            acc[2] = __builtin_amdgcn_mfma_f32_16x16x32_bf16(ha[ks], w2, acc[2], 0, 0, 0);
            acc[3] = __builtin_amdgcn_mfma_f32_16x16x32_bf16(ha[ks], w3, acc[3], 0, 0, 0);
        }

        // (6) partials -> LDS (D layout: col = lane&15, row = kblk*4 + r)
#pragma unroll
        for (int g = 0; g < 4; ++g)
#pragma unroll
            for (int r = 0; r < 4; ++r)
                gbuf[wv][kblk * 4 + r][g * 16 + c] = acc[g][r];
        __syncthreads();

        // (7) reduce 4 wave-partials + activations
        float gi = ((gbuf[0][eb][ 0+ej] + gbuf[1][eb][ 0+ej])
                  + (gbuf[2][eb][ 0+ej] + gbuf[3][eb][ 0+ej])) + bi;
        float gf = ((gbuf[0][eb][16+ej] + gbuf[1][eb][16+ej])
                  + (gbuf[2][eb][16+ej] + gbuf[3][eb][16+ej])) + bfv;
        float gg = ((gbuf[0][eb][32+ej] + gbuf[1][eb][32+ej])
                  + (gbuf[2][eb][32+ej] + gbuf[3][eb][32+ej])) + bg;
        float go = ((gbuf[0][eb][48+ej] + gbuf[1][eb][48+ej])
                  + (gbuf[2][eb][48+ej] + gbuf[3][eb][48+ej])) + bo;

        float I = sigmoid_f(gi);
        float F = sigmoid_f(gf);
        float G = tanh_f(gg);
        float O = sigmoid_f(go);
        cstate = F * cstate + I * G;
        float hval = O * tanh_f(cstate);

        y[((size_t)b_glob * T_ + t) * H_ + j_glob] = hval;  // 64B / 16 lanes

        // (8) 8B packed agent-scope h store (one store per 4 lanes)
        unsigned int mybf = (unsigned int)(unsigned short)f2bf(hval);
        unsigned int p01  = mybf | (((unsigned int)__shfl_xor((int)mybf, 1, 64)) << 16);
        unsigned int p23  = (unsigned int)__shfl_xor((int)p01, 2, 64);
        if ((ej & 3) == 0) {
            unsigned long long pk = (unsigned long long)p01
                                  | ((unsigned long long)p23 << 32);
            unsigned long long* hp = (unsigned long long*)
                (h_buf + ((t + 1) & 1) * (B_ * H_) + (size_t)b_glob * H_ + j_glob);
            __hip_atomic_store(hp, pk, __ATOMIC_RELAXED, __HIP_MEMORY_SCOPE_AGENT);
        }

        // (9) signal phase t+1: __syncthreads drains vmcnt in all waves ->
        // every sc-store acked at the coherence point before the flag store.
        __syncthreads();
        if (tid == 0)
            __hip_atomic_store(&flags[((bt << 6) | jt) * FLAG_STRIDE], t + 1,
                               __ATOMIC_RELAXED, __HIP_MEMORY_SCOPE_AGENT);
    }
}

extern "C" void kernel_launch(void* const* d_in, const int* in_sizes, int n_in,
                              void* d_out, int out_size, void* d_ws, size_t ws_size,
                              hipStream_t stream)
{
    const float* x    = (const float*)d_in[0];
    const float* Wx   = (const float*)d_in[1];
    const float* Wh   = (const float*)d_in[2];
    const float* bias = (const float*)d_in[3];
    float* y = (float*)d_out;

    char* ws = (char*)d_ws;
    const size_t h_bytes    = (size_t)2 * B_ * H_ * sizeof(short);      // 256 KB
    const size_t flag_bytes = (size_t)NWG * FLAG_STRIDE * sizeof(int);  // 16 KB
    short* h_buf = (short*)ws;
    int*   flags = (int*)(ws + h_bytes);

    // Re-init every call: h0 = 0; flags MUST be zeroed (stale phases from a
    // prior replay would let pollers race past the barrier).
    hipMemsetAsync(d_ws, 0, h_bytes + flag_bytes, stream);

    lstm_persistent<<<dim3(NWG), dim3(256), 0, stream>>>(
        x, Wx, Wh, bias, y, h_buf, flags);
}